// Round 2
// 412.821 us; speedup vs baseline: 1.0703x; 1.0703x over previous
//
#include <hip/hip_runtime.h>

#define PRE   1024
#define POST  1024
#define BATCH 256
#define HIST  50
#define NPAIR (PRE * POST)

typedef float nf4 __attribute__((ext_vector_type(4)));   // native vec for nontemporal builtins

// ---------------- kernel 1: batch means + EMA ----------------
__global__ __launch_bounds__(256) void means_kernel(
    const float* __restrict__ pre_spikes,   // [BATCH, PRE]
    const float* __restrict__ post_spikes,  // [BATCH, POST]
    const float* __restrict__ pre_activity, // [PRE]
    const float* __restrict__ post_activity,// [POST]
    float* __restrict__ ws_means,           // [PRE + POST] scratch
    float* __restrict__ out_pre_act,        // [PRE]
    float* __restrict__ out_post_act)       // [POST]
{
    __shared__ float red[256];
    int tid = threadIdx.x;
    int blk = blockIdx.x;
    bool is_pre = blk < 16;
    const float* mat = is_pre ? pre_spikes : post_spikes;
    const float* act = is_pre ? pre_activity : post_activity;
    float* out_act   = is_pre ? out_pre_act : out_post_act;
    float* ws        = is_pre ? ws_means : ws_means + PRE;
    int col0 = (blk & 15) * 64;

    int col = col0 + (tid & 63);
    int chunk = tid >> 6;                  // 0..3
    float s = 0.f;
#pragma unroll 8
    for (int r = chunk * 64; r < chunk * 64 + 64; ++r)
        s += mat[r * 1024 + col];
    red[tid] = s;
    __syncthreads();
    if (tid < 64) {
        float t = red[tid] + red[tid + 64] + red[tid + 128] + red[tid + 192];
        float m = t * (1.0f / BATCH);
        ws[col] = m;
        out_act[col] = 0.99f * act[col] + 0.01f * m;
    }
}

// ---------------- kernel 2: masked SGEMM, 64x64 tile, 4x4/thread, split-K x8 ----------------
// Inner loop per kk: 2 ds_read_b128 + 16 v_fmac (vs old 5 ds_read_b32 per 4 fmac).
// LDS rows padded to 68 floats (272 B) so every b128 access stays 16B-aligned;
// transposed-A scalar stores land as free 2-way bank conflicts.
#define GBM 64
#define GBN 64
#define GBK 16
#define GKSPLIT 8
#define GLD 68                      // padded leading dim for As/Bs
__global__ __launch_bounds__(256) void gemm_kernel(
    const float* __restrict__ A,   // [BATCH, PRE]
    const float* __restrict__ W,   // [PRE, POST]
    const float* __restrict__ Mk,  // [PRE, POST]
    float* __restrict__ C)         // [BATCH, POST]
{
    __shared__ __align__(16) float As[GBK * GLD];   // As[k][m] (transposed)
    __shared__ __align__(16) float Bs[GBK * GLD];   // Bs[k][n]
    int tid = threadIdx.x;
    int bn = blockIdx.x;           // 0..15 col tile
    int bm = blockIdx.y;           // 0..3  row tile
    int bz = blockIdx.z;           // 0..7  k split
    int kbase = bz * (PRE / GKSPLIT);

    // A staging: 64 rows x 16 k -> thread: row = tid>>2, k4 = (tid&3)*4
    int ar = tid >> 2;
    int ak = (tid & 3) << 2;
    // B staging: 16 k x 64 n -> thread: k = tid>>4, n4 = (tid&15)*4
    int bk = tid >> 4;
    int bn4 = (tid & 15) << 2;
    // compute mapping: 16x16 threads, 4x4 tile each
    int tn4 = (tid & 15) << 2;
    int tm4 = (tid >> 4) << 2;

    const float* Ap = &A[(bm * GBM + ar) * PRE + kbase + ak];
    const float* Wp = &W [(size_t)(kbase + bk) * POST + bn * GBN + bn4];
    const float* Mp = &Mk[(size_t)(kbase + bk) * POST + bn * GBN + bn4];

    float acc[4][4] = {};

    for (int k0 = 0; k0 < PRE / GKSPLIT; k0 += GBK) {
        float4 av = *(const float4*)(Ap + k0);
        float4 wv = *(const float4*)(Wp + (size_t)k0 * POST);
        float4 mv = *(const float4*)(Mp + (size_t)k0 * POST);
        wv.x *= mv.x; wv.y *= mv.y; wv.z *= mv.z; wv.w *= mv.w;
        __syncthreads();                       // protect previous iter's reads
        As[(ak + 0) * GLD + ar] = av.x;
        As[(ak + 1) * GLD + ar] = av.y;
        As[(ak + 2) * GLD + ar] = av.z;
        As[(ak + 3) * GLD + ar] = av.w;
        *(float4*)&Bs[bk * GLD + bn4] = wv;
        __syncthreads();
#pragma unroll
        for (int kk = 0; kk < GBK; ++kk) {
            float4 a4 = *(const float4*)&As[kk * GLD + tm4];
            float4 b4 = *(const float4*)&Bs[kk * GLD + tn4];
            const float* ap = (const float*)&a4;
            const float* bp = (const float*)&b4;
#pragma unroll
            for (int i = 0; i < 4; ++i)
#pragma unroll
                for (int j = 0; j < 4; ++j)
                    acc[i][j] += ap[i] * bp[j];
        }
    }
#pragma unroll
    for (int i = 0; i < 4; ++i)
#pragma unroll
        for (int j = 0; j < 4; ++j)
            atomicAdd(&C[(size_t)(bm * GBM + tm4 + i) * POST + bn * GBN + tn4 + j],
                      acc[i][j]);
}

// ---------------- kernel 3: history copy + in-flight scatter + mean ----------------
// 128 pairs/block (6400 floats = 1600 float4), 320 threads -> exactly 5
// float4 loads/thread. Slot idx is substituted IN the copied vector before
// both the LDS and global stores. The 200 MB hist_in read and 200 MB hist_out
// write are marked non-temporal (touch-once streams; WRITE_SIZE showed
// 471 MB vs the 214 MB minimum). Nontemporal builtins require native vector
// types -> nf4 (ext_vector_type), not HIP float4.
#define PPB 128
#define HTHREADS 320
#define NIT 5                      // 1600 / 320
__global__ __launch_bounds__(HTHREADS) void history_kernel(
    const float* __restrict__ hist_in,    // [PRE, POST, HIST]
    const int*   __restrict__ corr_index, // scalar
    const float* __restrict__ ws_means,   // [PRE + POST]
    float* __restrict__ hist_out,         // [PRE, POST, HIST]
    float* __restrict__ avg_out)          // [PRE, POST]
{
    __shared__ __align__(16) float tile[PPB * HIST];   // 25600 B
    int tid = threadIdx.x;
    int p0 = blockIdx.x * PPB;
    int idx = ((corr_index[0] % HIST) + HIST) % HIST;

    const nf4* in4   = (const nf4*)(hist_in + (size_t)p0 * HIST);
    nf4*       out4  = (nf4*)(hist_out + (size_t)p0 * HIST);
    nf4*       tile4 = (nf4*)tile;

    nf4 v[NIT];
#pragma unroll
    for (int it = 0; it < NIT; ++it)
        v[it] = __builtin_nontemporal_load(&in4[it * HTHREADS + tid]);

#pragma unroll
    for (int it = 0; it < NIT; ++it) {
        int fl = it * HTHREADS + tid;
        int r0 = 4 * fl;               // relative float index of component 0
        int pl = r0 / HIST;            // local pair of component 0
        int t0 = r0 - pl * HIST;       // slot of component 0
        int d  = idx - t0;             // component holding slot idx (same pair)
        int d2 = idx + HIST - t0;      // component holding slot idx (next pair)
        float* comps = (float*)&v[it];
        if (d >= 0 && d < 4) {
            int pair = p0 + pl;
            comps[d] = ws_means[pair >> 10] * ws_means[PRE + (pair & (POST - 1))];
        } else if (d2 < 4) {
            int pair = p0 + pl + 1;
            comps[d2] = ws_means[pair >> 10] * ws_means[PRE + (pair & (POST - 1))];
        }
        tile4[fl] = v[it];
        __builtin_nontemporal_store(v[it], &out4[fl]);
    }
    __syncthreads();

    if (tid < PPB) {
        int pair = p0 + tid;
        const float2* tp = (const float2*)&tile[tid * HIST];
        float s = 0.f;
#pragma unroll
        for (int k = 0; k < HIST / 2; ++k) {
            float2 w = tp[k];
            s += w.x + w.y;
        }
        __builtin_nontemporal_store(s * (1.0f / HIST), &avg_out[pair]);
    }
}

extern "C" void kernel_launch(void* const* d_in, const int* in_sizes, int n_in,
                              void* d_out, int out_size, void* d_ws, size_t ws_size,
                              hipStream_t stream)
{
    const float* pre_spikes  = (const float*)d_in[0];
    const float* post_spikes = (const float*)d_in[1];
    const float* W           = (const float*)d_in[2];
    const float* Mk          = (const float*)d_in[3];
    const float* hist        = (const float*)d_in[4];
    const float* pre_act     = (const float*)d_in[5];
    const float* post_act    = (const float*)d_in[6];
    const int*   corr_index  = (const int*)d_in[7];

    float* out = (float*)d_out;
    float* out_current  = out;                          // [256,1024]   262144
    float* out_pre_act  = out + 262144;                 // [1024]
    float* out_post_act = out + 263168;                 // [1024]
    float* out_avg      = out + 264192;                 // [1024,1024]  1048576
    float* out_hist     = out + 1312768;                // [1024,1024,50]

    float* ws_means = (float*)d_ws;                     // 2048 floats

    means_kernel<<<32, 256, 0, stream>>>(
        pre_spikes, post_spikes, pre_act, post_act,
        ws_means, out_pre_act, out_post_act);

    (void)hipMemsetAsync(out_current, 0, (size_t)BATCH * POST * sizeof(float), stream);

    gemm_kernel<<<dim3(POST / GBN, BATCH / GBM, GKSPLIT), 256, 0, stream>>>(
        pre_spikes, W, Mk, out_current);

    history_kernel<<<NPAIR / PPB, HTHREADS, 0, stream>>>(
        hist, corr_index, ws_means, out_hist, out_avg);
}

// Round 3
// 410.460 us; speedup vs baseline: 1.0764x; 1.0058x over previous
//
#include <hip/hip_runtime.h>

#define PRE   1024
#define POST  1024
#define BATCH 256
#define HIST  50
#define NPAIR (PRE * POST)

typedef float nf4 __attribute__((ext_vector_type(4)));   // native vec for nontemporal builtins

// ---------------- kernel 1: batch means + EMA ----------------
__global__ __launch_bounds__(256) void means_kernel(
    const float* __restrict__ pre_spikes,   // [BATCH, PRE]
    const float* __restrict__ post_spikes,  // [BATCH, POST]
    const float* __restrict__ pre_activity, // [PRE]
    const float* __restrict__ post_activity,// [POST]
    float* __restrict__ ws_means,           // [PRE + POST] scratch
    float* __restrict__ out_pre_act,        // [PRE]
    float* __restrict__ out_post_act)       // [POST]
{
    __shared__ float red[256];
    int tid = threadIdx.x;
    int blk = blockIdx.x;
    bool is_pre = blk < 16;
    const float* mat = is_pre ? pre_spikes : post_spikes;
    const float* act = is_pre ? pre_activity : post_activity;
    float* out_act   = is_pre ? out_pre_act : out_post_act;
    float* ws        = is_pre ? ws_means : ws_means + PRE;
    int col0 = (blk & 15) * 64;

    int col = col0 + (tid & 63);
    int chunk = tid >> 6;                  // 0..3
    float s = 0.f;
#pragma unroll 8
    for (int r = chunk * 64; r < chunk * 64 + 64; ++r)
        s += mat[r * 1024 + col];
    red[tid] = s;
    __syncthreads();
    if (tid < 64) {
        float t = red[tid] + red[tid + 64] + red[tid + 128] + red[tid + 192];
        float m = t * (1.0f / BATCH);
        ws[col] = m;
        out_act[col] = 0.99f * act[col] + 0.01f * m;
    }
}

// ---------------- kernel 2: masked SGEMM, 64x64 tile, 4x4/thread, split-K x8 ----------------
#define GBM 64
#define GBN 64
#define GBK 16
#define GKSPLIT 8
#define GLD 68                      // padded leading dim for As/Bs
__global__ __launch_bounds__(256) void gemm_kernel(
    const float* __restrict__ A,   // [BATCH, PRE]
    const float* __restrict__ W,   // [PRE, POST]
    const float* __restrict__ Mk,  // [PRE, POST]
    float* __restrict__ C)         // [BATCH, POST]
{
    __shared__ __align__(16) float As[GBK * GLD];   // As[k][m] (transposed)
    __shared__ __align__(16) float Bs[GBK * GLD];   // Bs[k][n]
    int tid = threadIdx.x;
    int bn = blockIdx.x;           // 0..15 col tile
    int bm = blockIdx.y;           // 0..3  row tile
    int bz = blockIdx.z;           // 0..7  k split
    int kbase = bz * (PRE / GKSPLIT);

    int ar = tid >> 2;
    int ak = (tid & 3) << 2;
    int bk = tid >> 4;
    int bn4 = (tid & 15) << 2;
    int tn4 = (tid & 15) << 2;
    int tm4 = (tid >> 4) << 2;

    const float* Ap = &A[(bm * GBM + ar) * PRE + kbase + ak];
    const float* Wp = &W [(size_t)(kbase + bk) * POST + bn * GBN + bn4];
    const float* Mp = &Mk[(size_t)(kbase + bk) * POST + bn * GBN + bn4];

    float acc[4][4] = {};

    for (int k0 = 0; k0 < PRE / GKSPLIT; k0 += GBK) {
        float4 av = *(const float4*)(Ap + k0);
        float4 wv = *(const float4*)(Wp + (size_t)k0 * POST);
        float4 mv = *(const float4*)(Mp + (size_t)k0 * POST);
        wv.x *= mv.x; wv.y *= mv.y; wv.z *= mv.z; wv.w *= mv.w;
        __syncthreads();                       // protect previous iter's reads
        As[(ak + 0) * GLD + ar] = av.x;
        As[(ak + 1) * GLD + ar] = av.y;
        As[(ak + 2) * GLD + ar] = av.z;
        As[(ak + 3) * GLD + ar] = av.w;
        *(float4*)&Bs[bk * GLD + bn4] = wv;
        __syncthreads();
#pragma unroll
        for (int kk = 0; kk < GBK; ++kk) {
            float4 a4 = *(const float4*)&As[kk * GLD + tm4];
            float4 b4 = *(const float4*)&Bs[kk * GLD + tn4];
            const float* ap = (const float*)&a4;
            const float* bp = (const float*)&b4;
#pragma unroll
            for (int i = 0; i < 4; ++i)
#pragma unroll
                for (int j = 0; j < 4; ++j)
                    acc[i][j] += ap[i] * bp[j];
        }
    }
#pragma unroll
    for (int i = 0; i < 4; ++i)
#pragma unroll
        for (int j = 0; j < 4; ++j)
            atomicAdd(&C[(size_t)(bm * GBM + tm4 + i) * POST + bn * GBN + tn4 + j],
                      acc[i][j]);
}

// ---------------- kernel 3: history copy + in-flight scatter + mean ----------------
// 128 pairs/block (6400 floats = 1600 float4), 320 threads -> exactly 5
// float4 loads/thread. FIX this round: the slot-idx substitution previously
// used a runtime-indexed component write (comps[d] = ...), which forced the
// whole v[] array to SCRATCH (VGPR_Count was 16!). Scratch dirty-line
// evictions were the +245 MB WRITE_SIZE amplification. Now each component is
// selected with a compile-time index (d==c / d2==c are mutually exclusive;
// d2 >= 1 always), so v[] stays in VGPRs and scratch traffic vanishes.
#define PPB 128
#define HTHREADS 320
#define NIT 5                      // 1600 / 320
__global__ __launch_bounds__(HTHREADS) void history_kernel(
    const float* __restrict__ hist_in,    // [PRE, POST, HIST]
    const int*   __restrict__ corr_index, // scalar
    const float* __restrict__ ws_means,   // [PRE + POST]
    float* __restrict__ hist_out,         // [PRE, POST, HIST]
    float* __restrict__ avg_out)          // [PRE, POST]
{
    __shared__ __align__(16) float tile[PPB * HIST];   // 25600 B
    int tid = threadIdx.x;
    int p0 = blockIdx.x * PPB;
    int idx = ((corr_index[0] % HIST) + HIST) % HIST;

    const nf4* in4   = (const nf4*)(hist_in + (size_t)p0 * HIST);
    nf4*       out4  = (nf4*)(hist_out + (size_t)p0 * HIST);
    nf4*       tile4 = (nf4*)tile;

    nf4 v[NIT];
#pragma unroll
    for (int it = 0; it < NIT; ++it)
        v[it] = __builtin_nontemporal_load(&in4[it * HTHREADS + tid]);

#pragma unroll
    for (int it = 0; it < NIT; ++it) {
        int fl = it * HTHREADS + tid;
        int r0 = 4 * fl;               // relative float index of component 0
        int pl = r0 / HIST;            // local pair of component 0
        int t0 = r0 - pl * HIST;       // slot of component 0
        int d  = idx - t0;             // component holding slot idx (pair pl)
        int d2 = idx + HIST - t0;      // component holding slot idx (pair pl+1), >= 1
        // Note: the last float4 of a block ends exactly on a pair boundary
        // (6400 = 128*50), so pairB <= p0+127 whenever d2 < 4; corrB reads
        // stay in ws_means bounds even when unused.
        int pairA = p0 + pl;
        int pairB = pairA + 1;
        float corrA = ws_means[pairA >> 10] * ws_means[PRE + (pairA & (POST - 1))];
        float corrB = ws_means[(pairB >> 10) & 1023] * ws_means[PRE + (pairB & (POST - 1))];
        nf4 w = v[it];
        w.x = (d == 0) ? corrA : w.x;                        // d2==0 impossible
        w.y = (d == 1) ? corrA : ((d2 == 1) ? corrB : w.y);
        w.z = (d == 2) ? corrA : ((d2 == 2) ? corrB : w.z);
        w.w = (d == 3) ? corrA : ((d2 == 3) ? corrB : w.w);
        tile4[fl] = w;
        __builtin_nontemporal_store(w, &out4[fl]);
    }
    __syncthreads();

    if (tid < PPB) {
        int pair = p0 + tid;
        const float2* tp = (const float2*)&tile[tid * HIST];
        float s = 0.f;
#pragma unroll
        for (int k = 0; k < HIST / 2; ++k) {
            float2 w = tp[k];
            s += w.x + w.y;
        }
        __builtin_nontemporal_store(s * (1.0f / HIST), &avg_out[pair]);
    }
}

extern "C" void kernel_launch(void* const* d_in, const int* in_sizes, int n_in,
                              void* d_out, int out_size, void* d_ws, size_t ws_size,
                              hipStream_t stream)
{
    const float* pre_spikes  = (const float*)d_in[0];
    const float* post_spikes = (const float*)d_in[1];
    const float* W           = (const float*)d_in[2];
    const float* Mk          = (const float*)d_in[3];
    const float* hist        = (const float*)d_in[4];
    const float* pre_act     = (const float*)d_in[5];
    const float* post_act    = (const float*)d_in[6];
    const int*   corr_index  = (const int*)d_in[7];

    float* out = (float*)d_out;
    float* out_current  = out;                          // [256,1024]   262144
    float* out_pre_act  = out + 262144;                 // [1024]
    float* out_post_act = out + 263168;                 // [1024]
    float* out_avg      = out + 264192;                 // [1024,1024]  1048576
    float* out_hist     = out + 1312768;                // [1024,1024,50]

    float* ws_means = (float*)d_ws;                     // 2048 floats

    means_kernel<<<32, 256, 0, stream>>>(
        pre_spikes, post_spikes, pre_act, post_act,
        ws_means, out_pre_act, out_post_act);

    (void)hipMemsetAsync(out_current, 0, (size_t)BATCH * POST * sizeof(float), stream);

    gemm_kernel<<<dim3(POST / GBN, BATCH / GBM, GKSPLIT), 256, 0, stream>>>(
        pre_spikes, W, Mk, out_current);

    history_kernel<<<NPAIR / PPB, HTHREADS, 0, stream>>>(
        hist, corr_index, ws_means, out_hist, out_avg);
}